// Round 1
// baseline (260.464 us; speedup 1.0000x reference)
//
#include <hip/hip_runtime.h>
#include <hip/hip_bf16.h>
#include <stdint.h>

#define B_ 8
#define T_ 2304
#define DIN 1024
#define LAMBDA_INIT_F 0.6192834728526788f

typedef __bf16 bf16x8 __attribute__((ext_vector_type(8)));
typedef float f32x4 __attribute__((ext_vector_type(4)));

__device__ __forceinline__ unsigned short f2bf(float f) {
    union { float f; unsigned int u; } v; v.f = f;
    unsigned int u = v.u;
    unsigned int r = (u + 0x7FFFu + ((u >> 16) & 1u)) >> 16;
    return (unsigned short)r;
}

// ---------------------------------------------------------------------------
// Kernel 1: transpose 9 weight mats (1024x128 f32) -> WT[seg][384][1024] bf16
// ---------------------------------------------------------------------------
__global__ __launch_bounds__(256) void k_wtrans(
    const float* w0, const float* w1, const float* w2,
    const float* w3, const float* w4, const float* w5,
    const float* w6, const float* w7, const float* w8,
    unsigned short* __restrict__ wt)
{
    __shared__ float tile[64][65];
    int bx = blockIdx.x;
    int mat = bx >> 5;
    int tl = bx & 31;
    int tx = tl & 15;      // k tile (0..15)
    int ty = tl >> 4;      // c tile (0..1)
    const float* srcs[9] = {w0, w1, w2, w3, w4, w5, w6, w7, w8};
    const float* src = srcs[mat];
    int k0 = tx * 64, c0 = ty * 64;
    int t = threadIdx.x;
    int r = t >> 2, cg = (t & 3) << 4;
    const float* p = src + (size_t)(k0 + r) * 128 + c0 + cg;
#pragma unroll
    for (int i = 0; i < 4; ++i) {
        float4 v = *(const float4*)(p + i * 4);
        tile[r][cg + i * 4 + 0] = v.x;
        tile[r][cg + i * 4 + 1] = v.y;
        tile[r][cg + i * 4 + 2] = v.z;
        tile[r][cg + i * 4 + 3] = v.w;
    }
    __syncthreads();
    int seg = mat / 3, m = mat % 3;
    int crow = seg * 384 + m * 128 + c0 + r;
    unsigned short* dst = wt + (size_t)crow * 1024 + k0 + cg;
    __align__(16) unsigned short ob[16];
#pragma unroll
    for (int i = 0; i < 16; ++i) ob[i] = f2bf(tile[cg + i][r]);
    *(uint4*)(dst) = *(const uint4*)(ob);
    *(uint4*)(dst + 8) = *(const uint4*)(ob + 8);
}

// ---------------------------------------------------------------------------
// Kernel 2: fused segment-LN + QKV projection.
// Block: 64 rows x 384 cols, 256 threads (4 waves), MFMA 16x16x32 bf16.
// Outputs: q,k [B][T][128] bf16 ; vT [B][128][T] bf16
// ---------------------------------------------------------------------------
__global__ __launch_bounds__(256) void k_proj(
    const float* __restrict__ x,
    const unsigned short* __restrict__ wt,
    const float* __restrict__ g_in, const float* __restrict__ b_in,
    const float* __restrict__ g_ss, const float* __restrict__ b_ss,
    const float* __restrict__ g_se, const float* __restrict__ b_se,
    unsigned short* __restrict__ qo,
    unsigned short* __restrict__ ko,
    unsigned short* __restrict__ vto)
{
    __shared__ unsigned short At[64 * 64];    // 8KB, rows of 128B, XOR-swizzled
    __shared__ unsigned short Wt[384 * 64];   // 48KB, rows of 128B, XOR-swizzled
    __shared__ float stats[64][2];

    int rt = blockIdx.x, b = blockIdx.y;
    int t0 = rt * 64;
    int seg = (rt < 2) ? 0 : ((rt < 34) ? 1 : 2);
    const float* gv = (seg == 0) ? g_ss : (seg == 1 ? g_in : g_se);
    const float* bv = (seg == 0) ? b_ss : (seg == 1 ? b_in : b_se);

    int tid = threadIdx.x;
    // LN stats: 4 threads per row
    {
        int r = tid >> 2, part = tid & 3;
        const float* xp = x + ((size_t)b * T_ + t0 + r) * DIN + part * 256;
        float s = 0.f, s2 = 0.f;
#pragma unroll 8
        for (int i = 0; i < 64; ++i) {
            float4 v = *(const float4*)(xp + i * 4);
            s += v.x + v.y + v.z + v.w;
            s2 += v.x * v.x + v.y * v.y + v.z * v.z + v.w * v.w;
        }
        s += __shfl_xor(s, 1);  s += __shfl_xor(s, 2);
        s2 += __shfl_xor(s2, 1); s2 += __shfl_xor(s2, 2);
        if (part == 0) {
            float mean = s * (1.f / 1024.f);
            float var = s2 * (1.f / 1024.f) - mean * mean;
            stats[r][0] = mean;
            stats[r][1] = rsqrtf(var + 1e-5f);
        }
    }
    __syncthreads();

    int w = tid >> 6, l = tid & 63;
    int wq = w * 96;
    f32x4 acc[4][6] = {};
    char* Ab = (char*)At;
    char* Wb = (char*)Wt;

    for (int ks = 0; ks < 16; ++ks) {
        int k0 = ks * 64;
        __syncthreads();
        // stage A (LN applied, bf16, swizzled)
        {
            int r = tid >> 2, cg = (tid & 3) << 4;
            const float* xp = x + ((size_t)b * T_ + t0 + r) * DIN + k0 + cg;
            float mean = stats[r][0], rs = stats[r][1];
            __align__(16) unsigned short tmp[16];
#pragma unroll
            for (int i = 0; i < 4; ++i) {
                float4 v = *(const float4*)(xp + i * 4);
                int kb = k0 + cg + i * 4;
                tmp[i * 4 + 0] = f2bf((v.x - mean) * rs * gv[kb + 0] + bv[kb + 0]);
                tmp[i * 4 + 1] = f2bf((v.y - mean) * rs * gv[kb + 1] + bv[kb + 1]);
                tmp[i * 4 + 2] = f2bf((v.z - mean) * rs * gv[kb + 2] + bv[kb + 2]);
                tmp[i * 4 + 3] = f2bf((v.w - mean) * rs * gv[kb + 3] + bv[kb + 3]);
            }
            int sw = (r & 7) << 4;
            *(uint4*)(Ab + r * 128 + ((cg * 2) ^ sw)) = *(const uint4*)(tmp);
            *(uint4*)(Ab + r * 128 + ((cg * 2 + 16) ^ sw)) = *(const uint4*)(tmp + 8);
        }
        // stage W^T tile (384 rows x 64 k, bf16, swizzled)
        {
            int u = tid & 7;
            int rbase = tid >> 3;
#pragma unroll
            for (int p = 0; p < 12; ++p) {
                int r2 = rbase + p * 32;
                const char* src = (const char*)(wt + ((size_t)(seg * 384 + r2) * 1024 + k0)) + u * 16;
                uint4 v = *(const uint4*)src;
                *(uint4*)(Wb + r2 * 128 + ((u * 16) ^ ((r2 & 7) << 4))) = v;
            }
        }
        __syncthreads();
#pragma unroll
        for (int kk = 0; kk < 2; ++kk) {
            bf16x8 af[4];
#pragma unroll
            for (int r4 = 0; r4 < 4; ++r4) {
                int rr = r4 * 16 + (l & 15);
                af[r4] = *(const bf16x8*)(Ab + rr * 128 + ((kk * 64 + ((l >> 4) * 16)) ^ ((rr & 7) << 4)));
            }
            bf16x8 bfr[6];
#pragma unroll
            for (int nt = 0; nt < 6; ++nt) {
                int c = wq + nt * 16 + (l & 15);
                bfr[nt] = *(const bf16x8*)(Wb + c * 128 + ((kk * 64 + ((l >> 4) * 16)) ^ ((c & 7) << 4)));
            }
#pragma unroll
            for (int r4 = 0; r4 < 4; ++r4)
#pragma unroll
                for (int nt = 0; nt < 6; ++nt)
                    acc[r4][nt] = __builtin_amdgcn_mfma_f32_16x16x32_bf16(af[r4], bfr[nt], acc[r4][nt], 0, 0, 0);
        }
    }
    // epilogue: C layout col=l&15, row=(l>>4)*4+reg
#pragma unroll
    for (int r4 = 0; r4 < 4; ++r4) {
        int tb = t0 + r4 * 16 + ((l >> 4) << 2);
#pragma unroll
        for (int nt = 0; nt < 6; ++nt) {
            int c = wq + nt * 16 + (l & 15);
            f32x4 a = acc[r4][nt];
            if (c < 128) {
#pragma unroll
                for (int g = 0; g < 4; ++g)
                    qo[((size_t)b * T_ + tb + g) * 128 + c] = f2bf(a[g]);
            } else if (c < 256) {
#pragma unroll
                for (int g = 0; g < 4; ++g)
                    ko[((size_t)b * T_ + tb + g) * 128 + (c - 128)] = f2bf(a[g]);
            } else {
                int cv = c - 256;
                __align__(8) unsigned short pk[4];
#pragma unroll
                for (int g = 0; g < 4; ++g) pk[g] = f2bf(a[g]);
                *(uint2*)(vto + ((size_t)b * 128 + cv) * T_ + tb) = *(const uint2*)pk;
            }
        }
    }
}

// ---------------------------------------------------------------------------
// Kernel 3: causal diff flash-attention + fused output LN.
// Block: 128 threads (2 waves), QB=32 (16 rows/wave), KB=64.
// Launched diagonal-descending for load balance.
// ---------------------------------------------------------------------------
__global__ __launch_bounds__(128) void k_attn(
    const unsigned short* __restrict__ qg,
    const unsigned short* __restrict__ kg,
    const unsigned short* __restrict__ vtg,
    const float* __restrict__ lq1, const float* __restrict__ lq2,
    const float* __restrict__ lk1, const float* __restrict__ lk2,
    const float* __restrict__ g_out, const float* __restrict__ b_out,
    float* __restrict__ out)
{
    __shared__ unsigned short Ks[64 * 128];   // 16KB, rows 256B, swizzled
    __shared__ unsigned short Vs[128 * 64];   // 16KB (V^T), rows 128B, swizzled
    __shared__ unsigned short Ps[2][16 * 64]; // per-wave P tile, swizzled

    int bid = blockIdx.x;
    int j = 71 - (bid >> 3);
    int b = bid & 7;
    int t0 = j * 32;
    int tid = threadIdx.x;
    int w = tid >> 6, l = tid & 63;

    float d1 = 0.f, d2 = 0.f;
#pragma unroll 16
    for (int i = 0; i < 64; ++i) {
        d1 += lq1[i] * lk1[i];
        d2 += lq2[i] * lk2[i];
    }
    float lam = __expf(d1) - __expf(d2) + LAMBDA_INIT_F;

    int trow = t0 + w * 16 + (l & 15);
    bf16x8 qf[2][2];
#pragma unroll
    for (int br = 0; br < 2; ++br)
#pragma unroll
        for (int kk = 0; kk < 2; ++kk)
            qf[br][kk] = *(const bf16x8*)(qg + ((size_t)b * T_ + trow) * 128 + br * 64 + kk * 32 + ((l >> 4) * 8));

    float mrun[2][4], lrun[2][4];
    f32x4 oacc[2][8] = {};
#pragma unroll
    for (int br = 0; br < 2; ++br)
#pragma unroll
        for (int g = 0; g < 4; ++g) { mrun[br][g] = -1e30f; lrun[br][g] = 0.f; }

    int kvend = (t0 + 31) >> 6;
    char* Kb = (char*)Ks;
    char* Vb = (char*)Vs;
    char* Pb = (char*)(Ps[w]);

    for (int kt = 0; kt <= kvend; ++kt) {
        __syncthreads();
        // stage K tile: 64 rows x 128 bf16 (both branches)
        {
            int r = tid >> 1, ub = (tid & 1) * 8;
            const char* src = (const char*)(kg + ((size_t)b * T_ + kt * 64 + r) * 128) + ub * 16;
            int sw = (r & 7) << 4;
#pragma unroll
            for (int i = 0; i < 8; ++i) {
                uint4 v = *(const uint4*)(src + i * 16);
                *(uint4*)(Kb + r * 256 + (((ub + i) * 16) ^ sw)) = v;
            }
        }
        // stage V^T tile: 128 rows x 64 bf16
        {
            int c = tid;
            const char* src = (const char*)(vtg + ((size_t)b * 128 + c) * T_ + kt * 64);
            int sw = (c & 7) << 4;
#pragma unroll
            for (int i = 0; i < 8; ++i) {
                uint4 v = *(const uint4*)(src + i * 16);
                *(uint4*)(Vb + c * 128 + ((i * 16) ^ sw)) = v;
            }
        }
        __syncthreads();

        bool diag = (kt == kvend);
#pragma unroll
        for (int br = 0; br < 2; ++br) {
            f32x4 s[4] = {};
#pragma unroll
            for (int kk = 0; kk < 2; ++kk) {
#pragma unroll
                for (int nt = 0; nt < 4; ++nt) {
                    int rk = nt * 16 + (l & 15);
                    bf16x8 kf = *(const bf16x8*)(Kb + rk * 256 + ((br * 128 + kk * 64 + ((l >> 4) * 16)) ^ ((rk & 7) << 4)));
                    s[nt] = __builtin_amdgcn_mfma_f32_16x16x32_bf16(qf[br][kk], kf, s[nt], 0, 0, 0);
                }
            }
            float sv[4][4];
            float mx[4] = {-1e30f, -1e30f, -1e30f, -1e30f};
#pragma unroll
            for (int nt = 0; nt < 4; ++nt) {
                int colg = kt * 64 + nt * 16 + (l & 15);
#pragma unroll
                for (int g = 0; g < 4; ++g) {
                    int rowg = t0 + w * 16 + ((l >> 4) << 2) + g;
                    float v = s[nt][g] * 0.125f;
                    if (diag && colg > rowg) v = -1e30f;
                    sv[nt][g] = v;
                    mx[g] = fmaxf(mx[g], v);
                }
            }
#pragma unroll
            for (int g = 0; g < 4; ++g) {
                mx[g] = fmaxf(mx[g], __shfl_xor(mx[g], 1));
                mx[g] = fmaxf(mx[g], __shfl_xor(mx[g], 2));
                mx[g] = fmaxf(mx[g], __shfl_xor(mx[g], 4));
                mx[g] = fmaxf(mx[g], __shfl_xor(mx[g], 8));
            }
            float sf[4], rs[4];
#pragma unroll
            for (int g = 0; g < 4; ++g) {
                float mn = fmaxf(mrun[br][g], mx[g]);
                sf[g] = __expf(mrun[br][g] - mn);
                mrun[br][g] = mn;
                rs[g] = 0.f;
            }
#pragma unroll
            for (int nt = 0; nt < 4; ++nt) {
#pragma unroll
                for (int g = 0; g < 4; ++g) {
                    float p = __expf(sv[nt][g] - mrun[br][g]);
                    rs[g] += p;
                    int rp = ((l >> 4) << 2) + g;
                    *(unsigned short*)(Pb + rp * 128 + ((nt * 32 + ((l & 15) * 2)) ^ ((rp & 7) << 4))) = f2bf(p);
                }
            }
#pragma unroll
            for (int g = 0; g < 4; ++g) {
                rs[g] += __shfl_xor(rs[g], 1);
                rs[g] += __shfl_xor(rs[g], 2);
                rs[g] += __shfl_xor(rs[g], 4);
                rs[g] += __shfl_xor(rs[g], 8);
                lrun[br][g] = lrun[br][g] * sf[g] + rs[g];
            }
#pragma unroll
            for (int n8 = 0; n8 < 8; ++n8)
#pragma unroll
                for (int g = 0; g < 4; ++g)
                    oacc[br][n8][g] *= sf[g];
            // PV
            bf16x8 pa[2];
#pragma unroll
            for (int kk = 0; kk < 2; ++kk) {
                int ra = l & 15;
                pa[kk] = *(const bf16x8*)(Pb + ra * 128 + ((kk * 64 + ((l >> 4) * 16)) ^ ((ra & 7) << 4)));
            }
#pragma unroll
            for (int n8 = 0; n8 < 8; ++n8) {
                int cv = n8 * 16 + (l & 15);
#pragma unroll
                for (int kk = 0; kk < 2; ++kk) {
                    bf16x8 vf = *(const bf16x8*)(Vb + cv * 128 + ((kk * 64 + ((l >> 4) * 16)) ^ ((cv & 7) << 4)));
                    oacc[br][n8] = __builtin_amdgcn_mfma_f32_16x16x32_bf16(pa[kk], vf, oacc[br][n8], 0, 0, 0);
                }
            }
        }
    }

    // epilogue: att = o1 - lam*o2, then LN over 128 cols, write f32
    float att[8][4];
    float smean[4] = {0.f, 0.f, 0.f, 0.f};
#pragma unroll
    for (int n8 = 0; n8 < 8; ++n8)
#pragma unroll
        for (int g = 0; g < 4; ++g) {
            float o1 = oacc[0][n8][g] / lrun[0][g];
            float o2 = oacc[1][n8][g] / lrun[1][g];
            float a = o1 - lam * o2;
            att[n8][g] = a;
            smean[g] += a;
        }
#pragma unroll
    for (int g = 0; g < 4; ++g) {
        smean[g] += __shfl_xor(smean[g], 1);
        smean[g] += __shfl_xor(smean[g], 2);
        smean[g] += __shfl_xor(smean[g], 4);
        smean[g] += __shfl_xor(smean[g], 8);
        smean[g] *= (1.f / 128.f);
    }
    float svar[4] = {0.f, 0.f, 0.f, 0.f};
#pragma unroll
    for (int n8 = 0; n8 < 8; ++n8)
#pragma unroll
        for (int g = 0; g < 4; ++g) {
            float d = att[n8][g] - smean[g];
            svar[g] += d * d;
        }
#pragma unroll
    for (int g = 0; g < 4; ++g) {
        svar[g] += __shfl_xor(svar[g], 1);
        svar[g] += __shfl_xor(svar[g], 2);
        svar[g] += __shfl_xor(svar[g], 4);
        svar[g] += __shfl_xor(svar[g], 8);
        svar[g] = rsqrtf(svar[g] * (1.f / 128.f) + 1e-5f);
    }
#pragma unroll
    for (int n8 = 0; n8 < 8; ++n8) {
        int c = n8 * 16 + (l & 15);
        float gg = g_out[c], bb = b_out[c];
#pragma unroll
        for (int g = 0; g < 4; ++g) {
            int t = t0 + w * 16 + ((l >> 4) << 2) + g;
            out[((size_t)b * T_ + t) * 128 + c] = (att[n8][g] - smean[g]) * svar[g] * gg + bb;
        }
    }
}

extern "C" void kernel_launch(void* const* d_in, const int* in_sizes, int n_in,
                              void* d_out, int out_size, void* d_ws, size_t ws_size,
                              hipStream_t stream) {
    (void)in_sizes; (void)n_in; (void)out_size; (void)ws_size;
    const float* x = (const float*)d_in[0];
    char* ws = (char*)d_ws;
    unsigned short* wt  = (unsigned short*)ws;                          // 3*384*1024*2 = 2359296 B
    unsigned short* qo  = (unsigned short*)(ws + 2359296);              // 4718592 B
    unsigned short* ko  = (unsigned short*)(ws + 2359296 + 4718592);    // 4718592 B
    unsigned short* vto = (unsigned short*)(ws + 2359296 + 2 * 4718592);// 4718592 B

    hipLaunchKernelGGL(k_wtrans, dim3(288), dim3(256), 0, stream,
        (const float*)d_in[4], (const float*)d_in[5], (const float*)d_in[6],
        (const float*)d_in[1], (const float*)d_in[2], (const float*)d_in[3],
        (const float*)d_in[7], (const float*)d_in[8], (const float*)d_in[9], wt);

    hipLaunchKernelGGL(k_proj, dim3(36, 8), dim3(256), 0, stream,
        x, wt,
        (const float*)d_in[10], (const float*)d_in[11],
        (const float*)d_in[12], (const float*)d_in[13],
        (const float*)d_in[14], (const float*)d_in[15],
        qo, ko, vto);

    hipLaunchKernelGGL(k_attn, dim3(576), dim3(128), 0, stream,
        qo, ko, vto,
        (const float*)d_in[18], (const float*)d_in[19],
        (const float*)d_in[20], (const float*)d_in[21],
        (const float*)d_in[16], (const float*)d_in[17],
        (float*)d_out);
}

// Round 2
// 201.754 us; speedup vs baseline: 1.2910x; 1.2910x over previous
//
#include <hip/hip_runtime.h>
#include <hip/hip_bf16.h>
#include <stdint.h>

#define B_ 8
#define T_ 2304
#define DIN 1024
#define LAMBDA_INIT_F 0.6192834728526788f

typedef __bf16 bf16x8 __attribute__((ext_vector_type(8)));
typedef float f32x4 __attribute__((ext_vector_type(4)));

__device__ __forceinline__ unsigned short f2bf(float f) {
    union { float f; unsigned int u; } v; v.f = f;
    unsigned int u = v.u;
    unsigned int r = (u + 0x7FFFu + ((u >> 16) & 1u)) >> 16;
    return (unsigned short)r;
}

__device__ __forceinline__ unsigned int pack2bf(float lo, float hi) {
    return ((unsigned int)f2bf(hi) << 16) | (unsigned int)f2bf(lo);
}

// ---------------------------------------------------------------------------
// Kernel 1: transpose 9 weight mats (1024x128 f32) -> WT[seg][384][1024] bf16
// ---------------------------------------------------------------------------
__global__ __launch_bounds__(256) void k_wtrans(
    const float* w0, const float* w1, const float* w2,
    const float* w3, const float* w4, const float* w5,
    const float* w6, const float* w7, const float* w8,
    unsigned short* __restrict__ wt)
{
    __shared__ float tile[64][65];
    int bx = blockIdx.x;
    int mat = bx >> 5;
    int tl = bx & 31;
    int tx = tl & 15;      // k tile (0..15)
    int ty = tl >> 4;      // c tile (0..1)
    const float* srcs[9] = {w0, w1, w2, w3, w4, w5, w6, w7, w8};
    const float* src = srcs[mat];
    int k0 = tx * 64, c0 = ty * 64;
    int t = threadIdx.x;
    int r = t >> 2, cg = (t & 3) << 4;
    const float* p = src + (size_t)(k0 + r) * 128 + c0 + cg;
#pragma unroll
    for (int i = 0; i < 4; ++i) {
        float4 v = *(const float4*)(p + i * 4);
        tile[r][cg + i * 4 + 0] = v.x;
        tile[r][cg + i * 4 + 1] = v.y;
        tile[r][cg + i * 4 + 2] = v.z;
        tile[r][cg + i * 4 + 3] = v.w;
    }
    __syncthreads();
    int seg = mat / 3, m = mat % 3;
    int crow = seg * 384 + m * 128 + c0 + r;
    unsigned short* dst = wt + (size_t)crow * 1024 + k0 + cg;
    __align__(16) unsigned short ob[16];
#pragma unroll
    for (int i = 0; i < 16; ++i) ob[i] = f2bf(tile[cg + i][r]);
    *(uint4*)(dst) = *(const uint4*)(ob);
    *(uint4*)(dst + 8) = *(const uint4*)(ob + 8);
}

// ---------------------------------------------------------------------------
// Kernel 2: fused segment-LN + QKV projection.
// Block: 64 rows x 384 cols, 256 threads (4 waves), MFMA 16x16x32 bf16.
// Outputs: q,k [B][T][128] bf16 ; vT [B][128][T] bf16
// ---------------------------------------------------------------------------
__global__ __launch_bounds__(256) void k_proj(
    const float* __restrict__ x,
    const unsigned short* __restrict__ wt,
    const float* __restrict__ g_in, const float* __restrict__ b_in,
    const float* __restrict__ g_ss, const float* __restrict__ b_ss,
    const float* __restrict__ g_se, const float* __restrict__ b_se,
    unsigned short* __restrict__ qo,
    unsigned short* __restrict__ ko,
    unsigned short* __restrict__ vto)
{
    __shared__ unsigned short At[64 * 64];    // 8KB, rows of 128B, XOR-swizzled
    __shared__ unsigned short Wt[384 * 64];   // 48KB, rows of 128B, XOR-swizzled
    __shared__ float stats[64][2];

    int rt = blockIdx.x, b = blockIdx.y;
    int t0 = rt * 64;
    int seg = (rt < 2) ? 0 : ((rt < 34) ? 1 : 2);
    const float* gv = (seg == 0) ? g_ss : (seg == 1 ? g_in : g_se);
    const float* bv = (seg == 0) ? b_ss : (seg == 1 ? b_in : b_se);

    int tid = threadIdx.x;
    // LN stats: 4 threads per row
    {
        int r = tid >> 2, part = tid & 3;
        const float* xp = x + ((size_t)b * T_ + t0 + r) * DIN + part * 256;
        float s = 0.f, s2 = 0.f;
#pragma unroll 8
        for (int i = 0; i < 64; ++i) {
            float4 v = *(const float4*)(xp + i * 4);
            s += v.x + v.y + v.z + v.w;
            s2 += v.x * v.x + v.y * v.y + v.z * v.z + v.w * v.w;
        }
        s += __shfl_xor(s, 1);  s += __shfl_xor(s, 2);
        s2 += __shfl_xor(s2, 1); s2 += __shfl_xor(s2, 2);
        if (part == 0) {
            float mean = s * (1.f / 1024.f);
            float var = s2 * (1.f / 1024.f) - mean * mean;
            stats[r][0] = mean;
            stats[r][1] = rsqrtf(var + 1e-5f);
        }
    }
    __syncthreads();

    int w = tid >> 6, l = tid & 63;
    int wq = w * 96;
    f32x4 acc[4][6] = {};
    char* Ab = (char*)At;
    char* Wb = (char*)Wt;

    for (int ks = 0; ks < 16; ++ks) {
        int k0 = ks * 64;
        __syncthreads();
        // stage A (LN applied, bf16, swizzled)
        {
            int r = tid >> 2, cg = (tid & 3) << 4;
            const float* xp = x + ((size_t)b * T_ + t0 + r) * DIN + k0 + cg;
            float mean = stats[r][0], rs = stats[r][1];
            __align__(16) unsigned short tmp[16];
#pragma unroll
            for (int i = 0; i < 4; ++i) {
                float4 v = *(const float4*)(xp + i * 4);
                int kb = k0 + cg + i * 4;
                tmp[i * 4 + 0] = f2bf((v.x - mean) * rs * gv[kb + 0] + bv[kb + 0]);
                tmp[i * 4 + 1] = f2bf((v.y - mean) * rs * gv[kb + 1] + bv[kb + 1]);
                tmp[i * 4 + 2] = f2bf((v.z - mean) * rs * gv[kb + 2] + bv[kb + 2]);
                tmp[i * 4 + 3] = f2bf((v.w - mean) * rs * gv[kb + 3] + bv[kb + 3]);
            }
            int sw = (r & 7) << 4;
            *(uint4*)(Ab + r * 128 + ((cg * 2) ^ sw)) = *(const uint4*)(tmp);
            *(uint4*)(Ab + r * 128 + ((cg * 2 + 16) ^ sw)) = *(const uint4*)(tmp + 8);
        }
        // stage W^T tile (384 rows x 64 k, bf16, swizzled)
        {
            int u = tid & 7;
            int rbase = tid >> 3;
#pragma unroll
            for (int p = 0; p < 12; ++p) {
                int r2 = rbase + p * 32;
                const char* src = (const char*)(wt + ((size_t)(seg * 384 + r2) * 1024 + k0)) + u * 16;
                uint4 v = *(const uint4*)src;
                *(uint4*)(Wb + r2 * 128 + ((u * 16) ^ ((r2 & 7) << 4))) = v;
            }
        }
        __syncthreads();
#pragma unroll
        for (int kk = 0; kk < 2; ++kk) {
            bf16x8 af[4];
#pragma unroll
            for (int r4 = 0; r4 < 4; ++r4) {
                int rr = r4 * 16 + (l & 15);
                af[r4] = *(const bf16x8*)(Ab + rr * 128 + ((kk * 64 + ((l >> 4) * 16)) ^ ((rr & 7) << 4)));
            }
            bf16x8 bfr[6];
#pragma unroll
            for (int nt = 0; nt < 6; ++nt) {
                int c = wq + nt * 16 + (l & 15);
                bfr[nt] = *(const bf16x8*)(Wb + c * 128 + ((kk * 64 + ((l >> 4) * 16)) ^ ((c & 7) << 4)));
            }
#pragma unroll
            for (int r4 = 0; r4 < 4; ++r4)
#pragma unroll
                for (int nt = 0; nt < 6; ++nt)
                    acc[r4][nt] = __builtin_amdgcn_mfma_f32_16x16x32_bf16(af[r4], bfr[nt], acc[r4][nt], 0, 0, 0);
        }
    }
    // epilogue: C layout col=l&15, row=(l>>4)*4+reg
#pragma unroll
    for (int r4 = 0; r4 < 4; ++r4) {
        int tb = t0 + r4 * 16 + ((l >> 4) << 2);
#pragma unroll
        for (int nt = 0; nt < 6; ++nt) {
            int c = wq + nt * 16 + (l & 15);
            f32x4 a = acc[r4][nt];
            if (c < 128) {
#pragma unroll
                for (int g = 0; g < 4; ++g)
                    qo[((size_t)b * T_ + tb + g) * 128 + c] = f2bf(a[g]);
            } else if (c < 256) {
#pragma unroll
                for (int g = 0; g < 4; ++g)
                    ko[((size_t)b * T_ + tb + g) * 128 + (c - 128)] = f2bf(a[g]);
            } else {
                int cv = c - 256;
                __align__(8) unsigned short pk[4];
#pragma unroll
                for (int g = 0; g < 4; ++g) pk[g] = f2bf(a[g]);
                *(uint2*)(vto + ((size_t)b * 128 + cv) * T_ + tb) = *(const uint2*)pk;
            }
        }
    }
}

// ---------------------------------------------------------------------------
// Kernel 3: causal diff flash-attention + fused output LN.
// Swapped-operand design: S^T = mfma(K, Q) puts q in lanes, kv in regs ->
// in-lane softmax, P stays in registers (shfl-repack to PV B-frag).
// O^T = mfma(V^T, P^T) -> output LN is in-lane.
// Block: 256 threads (4 waves), QB=64 (16 q-rows/wave), KB=64.
// ---------------------------------------------------------------------------
__global__ __launch_bounds__(256) void k_attn(
    const unsigned short* __restrict__ qg,
    const unsigned short* __restrict__ kg,
    const unsigned short* __restrict__ vtg,
    const float* __restrict__ lq1, const float* __restrict__ lq2,
    const float* __restrict__ lk1, const float* __restrict__ lk2,
    const float* __restrict__ g_out, const float* __restrict__ b_out,
    float* __restrict__ out)
{
    __shared__ unsigned short Ks[64 * 128];   // 16KB, rows 256B, swizzled
    __shared__ unsigned short Vs[128 * 64];   // 16KB (V^T), rows 128B, swizzled

    int bid = blockIdx.x;
    int j = 35 - (bid >> 3);         // descending: big (diagonal-long) tiles first
    int b = bid & 7;
    int t0 = j * 64;
    int tid = threadIdx.x;
    int wq = tid >> 6, l = tid & 63;
    int g4 = l >> 4, q = l & 15;

    float d1 = 0.f, d2 = 0.f;
#pragma unroll 16
    for (int i = 0; i < 64; ++i) {
        d1 += lq1[i] * lk1[i];
        d2 += lq2[i] * lk2[i];
    }
    float lam = __expf(d1) - __expf(d2) + LAMBDA_INIT_F;

    int q_g = t0 + wq * 16 + q;
    // Q B-fragments (held for whole kernel): B[k=d][col=q]
    bf16x8 qf[2][2];
#pragma unroll
    for (int br = 0; br < 2; ++br)
#pragma unroll
        for (int w = 0; w < 2; ++w)
            qf[br][w] = *(const bf16x8*)(qg + ((size_t)b * T_ + q_g) * 128 + br * 64 + w * 32 + g4 * 8);

    float mrun[2] = {-1e30f, -1e30f};
    float lrun[2] = {0.f, 0.f};
    f32x4 oacc[2][8] = {};

    char* Kb = (char*)Ks;
    char* Vb = (char*)Vs;

    for (int kt = 0; kt <= j; ++kt) {
        __syncthreads();
        // stage K tile: 64 rows x 256B, 256 threads x 64B
        {
            int r = tid >> 2, qt = (tid & 3) << 6;
            const char* src = (const char*)(kg + ((size_t)b * T_ + kt * 64 + r) * 128) + qt;
            int sw = (r & 7) << 4;
#pragma unroll
            for (int i = 0; i < 4; ++i) {
                uint4 v = *(const uint4*)(src + i * 16);
                *(uint4*)(Kb + r * 256 + ((qt + i * 16) ^ sw)) = v;
            }
        }
        // stage V^T tile: 128 rows x 128B, 256 threads x 64B
        {
            int r = tid >> 1, hf = (tid & 1) << 6;
            const char* src = (const char*)(vtg + ((size_t)b * 128 + r) * T_ + kt * 64) + hf;
            int sw = (r & 7) << 4;
#pragma unroll
            for (int i = 0; i < 4; ++i) {
                uint4 v = *(const uint4*)(src + i * 16);
                *(uint4*)(Vb + r * 128 + ((hf + i * 16) ^ sw)) = v;
            }
        }
        __syncthreads();

        bool diag = (kt == j);
        unsigned int pk[2][4][2];
#pragma unroll
        for (int br = 0; br < 2; ++br) {
            // S^T = K @ Q^T : lane holds 16 kv values for its single q
            f32x4 s[4] = {};
#pragma unroll
            for (int w = 0; w < 2; ++w) {
#pragma unroll
                for (int t = 0; t < 4; ++t) {
                    int rk = t * 16 + q;
                    bf16x8 kf = *(const bf16x8*)(Kb + rk * 256 + ((br * 128 + w * 64 + g4 * 16) ^ ((rk & 7) << 4)));
                    s[t] = __builtin_amdgcn_mfma_f32_16x16x32_bf16(kf, qf[br][w], s[t], 0, 0, 0);
                }
            }
            // in-lane softmax over 16 values + 2 cross-group shuffles
            float sv[16];
            float mx = -1e30f;
#pragma unroll
            for (int t = 0; t < 4; ++t)
#pragma unroll
                for (int r = 0; r < 4; ++r) {
                    float v = s[t][r] * 0.125f;
                    if (diag) {
                        int kv_g = kt * 64 + t * 16 + g4 * 4 + r;
                        if (kv_g > q_g) v = -1e30f;
                    }
                    sv[t * 4 + r] = v;
                    mx = fmaxf(mx, v);
                }
            mx = fmaxf(mx, __shfl_xor(mx, 16));
            mx = fmaxf(mx, __shfl_xor(mx, 32));
            float mn = fmaxf(mrun[br], mx);
            float sf = __expf(mrun[br] - mn);
            mrun[br] = mn;
            float p[16];
            float rs = 0.f;
#pragma unroll
            for (int i = 0; i < 16; ++i) {
                p[i] = __expf(sv[i] - mn);
                rs += p[i];
            }
            rs += __shfl_xor(rs, 16);
            rs += __shfl_xor(rs, 32);
            lrun[br] = lrun[br] * sf + rs;
#pragma unroll
            for (int dblk = 0; dblk < 8; ++dblk)
#pragma unroll
                for (int r = 0; r < 4; ++r)
                    oacc[br][dblk][r] *= sf;
            // pack P (bf16 pairs), kv-pairs within each 16-kv block
#pragma unroll
            for (int t = 0; t < 4; ++t) {
                pk[br][t][0] = pack2bf(p[t * 4 + 0], p[t * 4 + 1]);
                pk[br][t][1] = pack2bf(p[t * 4 + 2], p[t * 4 + 3]);
            }
        }

        // PV: O^T += V^T @ P^T ; build P^T B-frag via shfl repack
#pragma unroll
        for (int w = 0; w < 2; ++w) {
            bf16x8 pb[2];
            int s0 = q + (((g4 * 2) & 3) << 4);
            int s1 = q + (((g4 * 2 + 1) & 3) << 4);
            int sel = g4 >> 1;
#pragma unroll
            for (int br = 0; br < 2; ++br) {
                unsigned int m0a = (unsigned int)__shfl((int)pk[br][2 * w][0], s0);
                unsigned int m0b = (unsigned int)__shfl((int)pk[br][2 * w + 1][0], s0);
                unsigned int m1a = (unsigned int)__shfl((int)pk[br][2 * w][1], s0);
                unsigned int m1b = (unsigned int)__shfl((int)pk[br][2 * w + 1][1], s0);
                unsigned int m2a = (unsigned int)__shfl((int)pk[br][2 * w][0], s1);
                unsigned int m2b = (unsigned int)__shfl((int)pk[br][2 * w + 1][0], s1);
                unsigned int m3a = (unsigned int)__shfl((int)pk[br][2 * w][1], s1);
                unsigned int m3b = (unsigned int)__shfl((int)pk[br][2 * w + 1][1], s1);
                union { unsigned int u[4]; bf16x8 v; } pu;
                pu.u[0] = sel ? m0b : m0a;
                pu.u[1] = sel ? m1b : m1a;
                pu.u[2] = sel ? m2b : m2a;
                pu.u[3] = sel ? m3b : m3a;
                pb[br] = pu.v;
            }
#pragma unroll
            for (int dblk = 0; dblk < 8; ++dblk) {
                int rv = dblk * 16 + q;
                bf16x8 vf = *(const bf16x8*)(Vb + rv * 128 + ((w * 64 + g4 * 16) ^ ((rv & 7) << 4)));
                oacc[0][dblk] = __builtin_amdgcn_mfma_f32_16x16x32_bf16(vf, pb[0], oacc[0][dblk], 0, 0, 0);
                oacc[1][dblk] = __builtin_amdgcn_mfma_f32_16x16x32_bf16(vf, pb[1], oacc[1][dblk], 0, 0, 0);
            }
        }
    }

    // epilogue: att = o1 - lam*o2 (per-lane: one q row, 32 of 128 d values)
    float att[8][4];
    float sm = 0.f;
    float inv1 = 1.f / lrun[0], inv2 = 1.f / lrun[1];
#pragma unroll
    for (int dblk = 0; dblk < 8; ++dblk)
#pragma unroll
        for (int r = 0; r < 4; ++r) {
            float a = oacc[0][dblk][r] * inv1 - lam * (oacc[1][dblk][r] * inv2);
            att[dblk][r] = a;
            sm += a;
        }
    sm += __shfl_xor(sm, 16);
    sm += __shfl_xor(sm, 32);
    float mean = sm * (1.f / 128.f);
    float sv2 = 0.f;
#pragma unroll
    for (int dblk = 0; dblk < 8; ++dblk)
#pragma unroll
        for (int r = 0; r < 4; ++r) {
            float d = att[dblk][r] - mean;
            sv2 += d * d;
        }
    sv2 += __shfl_xor(sv2, 16);
    sv2 += __shfl_xor(sv2, 32);
    float rstd = rsqrtf(sv2 * (1.f / 128.f) + 1e-5f);

    float* orow = out + ((size_t)b * T_ + q_g) * 128;
#pragma unroll
    for (int dblk = 0; dblk < 8; ++dblk) {
        int d0 = dblk * 16 + g4 * 4;
        float4 o;
        o.x = (att[dblk][0] - mean) * rstd * g_out[d0 + 0] + b_out[d0 + 0];
        o.y = (att[dblk][1] - mean) * rstd * g_out[d0 + 1] + b_out[d0 + 1];
        o.z = (att[dblk][2] - mean) * rstd * g_out[d0 + 2] + b_out[d0 + 2];
        o.w = (att[dblk][3] - mean) * rstd * g_out[d0 + 3] + b_out[d0 + 3];
        *(float4*)(orow + d0) = o;
    }
}

extern "C" void kernel_launch(void* const* d_in, const int* in_sizes, int n_in,
                              void* d_out, int out_size, void* d_ws, size_t ws_size,
                              hipStream_t stream) {
    (void)in_sizes; (void)n_in; (void)out_size; (void)ws_size;
    const float* x = (const float*)d_in[0];
    char* ws = (char*)d_ws;
    unsigned short* wt  = (unsigned short*)ws;                          // 3*384*1024*2 = 2359296 B
    unsigned short* qo  = (unsigned short*)(ws + 2359296);              // 4718592 B
    unsigned short* ko  = (unsigned short*)(ws + 2359296 + 4718592);    // 4718592 B
    unsigned short* vto = (unsigned short*)(ws + 2359296 + 2 * 4718592);// 4718592 B

    hipLaunchKernelGGL(k_wtrans, dim3(288), dim3(256), 0, stream,
        (const float*)d_in[4], (const float*)d_in[5], (const float*)d_in[6],
        (const float*)d_in[1], (const float*)d_in[2], (const float*)d_in[3],
        (const float*)d_in[7], (const float*)d_in[8], (const float*)d_in[9], wt);

    hipLaunchKernelGGL(k_proj, dim3(36, 8), dim3(256), 0, stream,
        x, wt,
        (const float*)d_in[10], (const float*)d_in[11],
        (const float*)d_in[12], (const float*)d_in[13],
        (const float*)d_in[14], (const float*)d_in[15],
        qo, ko, vto);

    hipLaunchKernelGGL(k_attn, dim3(288), dim3(256), 0, stream,
        qo, ko, vto,
        (const float*)d_in[18], (const float*)d_in[19],
        (const float*)d_in[20], (const float*)d_in[21],
        (const float*)d_in[16], (const float*)d_in[17],
        (float*)d_out);
}